// Round 4
// baseline (286.608 us; speedup 1.0000x reference)
//
#include <hip/hip_runtime.h>

#define BATCH 32
#define SEQ 512
#define CH4 96            // float4 per channel row (384 ch)
#define MAXL 4096
#define FPB 8             // frames per block
#define CPB 64            // chunks (blocks) per batch = SEQ/FPB
#define THREADS 128
#define STORE_PASSES 4    // DIAGNOSTIC: 1 real + 3 idempotent repeats

typedef float v4f __attribute__((ext_vector_type(4)));
typedef int   v4i __attribute__((ext_vector_type(4)));

// R10 — DIAGNOSTIC build of the best-known R6 scatter kernel.
// Purpose: the kernel has never appeared in the rocprof top-5 (cutoff
// ~121us poison fills), so its true duration / WRITE_SIZE / FETCH_SIZE /
// occupancy are unknown; two accounting models (kernel=93us w/ 59us
// headroom vs kernel=40us already at roofline) fit all data so far.
// The store phase runs STORE_PASSES times (idempotent: same values to
// same addresses; compiler barrier prevents dead-store elimination).
// The +3 passes (~600MB extra stores) push the kernel above the top-5
// cutoff AND measure the marginal cost of one scatter store pass.
__global__ __launch_bounds__(THREADS) void lr_fused_diag(
    const v4f* __restrict__ x,
    const v4i* __restrict__ dur4,
    const int* __restrict__ max_len_p,
    v4f* __restrict__ out,
    float* __restrict__ out_mask)
{
    __shared__ int s_end[SEQ];

    const int tid   = threadIdx.x;
    const int bid   = blockIdx.x;
    const int b     = bid >> 6;            // CPB = 64
    const int chunk = bid & (CPB - 1);
    const int j0    = chunk * FPB;

    // --- 1. front-loaded x-row reads (independent of the scan) ---
    v4f vx[FPB];
    if (tid < CH4) {
        const v4f* xp = x + ((size_t)(b * SEQ + j0)) * CH4 + tid;
        #pragma unroll
        for (int fr = 0; fr < FPB; ++fr) vx[fr] = xp[fr * CH4];
    }

    // --- 2. wave-0 scan: 512 durations -> clipped inclusive ends (R6-proven) ---
    if (tid < 64) {
        const v4i* dp = dur4 + b * (SEQ / 4) + tid * 2;   // 8 ints/lane
        v4i d0 = dp[0], d1 = dp[1];
        int lane_sum = d0.x + d0.y + d0.z + d0.w + d1.x + d1.y + d1.z + d1.w;
        int incl = lane_sum;
        #pragma unroll
        for (int off = 1; off < 64; off <<= 1) {
            int v = __shfl_up(incl, off, 64);
            if (tid >= off) incl += v;
        }
        int cum = incl - lane_sum;                        // exclusive prefix
        const int maxlen = max_len_p[0];
        const int base = tid * 8;
        cum += d0.x; s_end[base + 0] = min(cum, maxlen);
        cum += d0.y; s_end[base + 1] = min(cum, maxlen);
        cum += d0.z; s_end[base + 2] = min(cum, maxlen);
        cum += d0.w; s_end[base + 3] = min(cum, maxlen);
        cum += d1.x; s_end[base + 4] = min(cum, maxlen);
        cum += d1.y; s_end[base + 5] = min(cum, maxlen);
        cum += d1.z; s_end[base + 6] = min(cum, maxlen);
        cum += d1.w; s_end[base + 7] = min(cum, maxlen);
    }
    __syncthreads();

    const int st0   = j0 ? s_end[j0 - 1] : 0;
    const int e7    = s_end[j0 + FPB - 1];
    const int total = s_end[SEQ - 1];

    // --- 3. mask zeros for this chunk's covered rows (<= 8*15 = 120 < 128) ---
    if (tid < e7 - st0) out_mask[(b << 12) + st0 + tid] = 0.0f;

    // --- 4. store phase, repeated STORE_PASSES times (diagnostic) ---
    if (tid < CH4) {
        #pragma unroll 1
        for (int pass = 0; pass < STORE_PASSES; ++pass) {
            v4f* const ob_base = out + ((size_t)(b << 12)) * CH4 + tid;
            #pragma unroll
            for (int fr = 0; fr < FPB; ++fr) {
                const int jj = j0 + fr;
                const int e  = s_end[jj];
                const int st = jj ? s_end[jj - 1] : 0;
                v4f v = vx[fr];
                v4f* ob = ob_base + (size_t)st * CH4;
                for (int t = st; t < e; ++t) {
                    *ob = v;
                    ob += CH4;
                }
            }
            // compiler barrier: forbids dead-store elimination of earlier
            // passes and cross-pass merging; no runtime cost
            asm volatile("" ::: "memory");
        }
    }

    // --- 5. tail zero rows [total, MAXL), strided across the 64 chunks ---
    const v4f zero = (v4f){0.f, 0.f, 0.f, 0.f};
    for (int t = total + chunk; t < MAXL; t += CPB) {
        if (tid < CH4)
            out[((size_t)(b << 12) + t) * CH4 + tid] = zero;
        else if (tid == CH4)
            out_mask[(b << 12) + t] = 1.0f;
    }
}

extern "C" void kernel_launch(void* const* d_in, const int* in_sizes, int n_in,
                              void* d_out, int out_size, void* d_ws, size_t ws_size,
                              hipStream_t stream) {
    const v4f* x = (const v4f*)d_in[0];
    const v4i* dur4 = (const v4i*)d_in[1];
    const int* max_len_p = (const int*)d_in[2];
    float* out = (float*)d_out;
    float* out_mask = out + (size_t)BATCH * MAXL * CH4 * 4;

    lr_fused_diag<<<BATCH * CPB, THREADS, 0, stream>>>(
        x, dur4, max_len_p, (v4f*)out, out_mask);
}

// Round 5
// 215.536 us; speedup vs baseline: 1.3297x; 1.3297x over previous
//
#include <hip/hip_runtime.h>

#define BATCH 32
#define SEQ 512
#define CH4 96            // float4 per channel row (384 ch)
#define MAXL 4096
#define FPB 8             // frames per block
#define CPB 64            // chunks (blocks) per batch = SEQ/FPB
#define THREADS 128

typedef float v4f __attribute__((ext_vector_type(4)));
typedef int   v4i __attribute__((ext_vector_type(4)));

// R11 = R6 scatter, restored after the R10 diagnostic settled the accounting.
// R10 evidence (4x idempotent store passes pushed the kernel into the
// rocprof top-5): WRITE_SIZE ~740MB == hand-computed 4x189MB+tail (no RFO,
// no amplification), FETCH ~12.6MB (x is L3-resident), 6.31 TB/s = 79% of
// HBM peak vs the harness fill's 82%. Marginal store pass = 567MB/88us =
// 6.4 TB/s. => single-pass kernel is ~34-40us, within ~10% of its 34us
// memory roofline (215MB traffic). The 216us bench total is 121us poison
// fill + ~55us fixed harness resets + this kernel; remaining kernel
// headroom ~6us < bench noise. R7-R9 restructures (gather, two-phase,
// nt-stores) all regressed: they added structural cost to an
// already-roofline-bound 40us kernel.
__global__ __launch_bounds__(THREADS) void lr_fused(
    const v4f* __restrict__ x,
    const v4i* __restrict__ dur4,
    const int* __restrict__ max_len_p,
    v4f* __restrict__ out,
    float* __restrict__ out_mask)
{
    __shared__ int s_end[SEQ];

    const int tid   = threadIdx.x;
    const int bid   = blockIdx.x;
    const int b     = bid >> 6;            // CPB = 64
    const int chunk = bid & (CPB - 1);
    const int j0    = chunk * FPB;

    // --- 1. front-loaded x-row reads (independent of the scan) ---
    v4f vx[FPB];
    if (tid < CH4) {
        const v4f* xp = x + ((size_t)(b * SEQ + j0)) * CH4 + tid;
        #pragma unroll
        for (int fr = 0; fr < FPB; ++fr) vx[fr] = xp[fr * CH4];
    }

    // --- 2. wave-0 scan: 512 durations -> clipped inclusive ends (R6-proven) ---
    if (tid < 64) {
        const v4i* dp = dur4 + b * (SEQ / 4) + tid * 2;   // 8 ints/lane
        v4i d0 = dp[0], d1 = dp[1];
        int lane_sum = d0.x + d0.y + d0.z + d0.w + d1.x + d1.y + d1.z + d1.w;
        int incl = lane_sum;
        #pragma unroll
        for (int off = 1; off < 64; off <<= 1) {
            int v = __shfl_up(incl, off, 64);
            if (tid >= off) incl += v;
        }
        int cum = incl - lane_sum;                        // exclusive prefix
        const int maxlen = max_len_p[0];
        const int base = tid * 8;
        cum += d0.x; s_end[base + 0] = min(cum, maxlen);
        cum += d0.y; s_end[base + 1] = min(cum, maxlen);
        cum += d0.z; s_end[base + 2] = min(cum, maxlen);
        cum += d0.w; s_end[base + 3] = min(cum, maxlen);
        cum += d1.x; s_end[base + 4] = min(cum, maxlen);
        cum += d1.y; s_end[base + 5] = min(cum, maxlen);
        cum += d1.z; s_end[base + 6] = min(cum, maxlen);
        cum += d1.w; s_end[base + 7] = min(cum, maxlen);
    }
    __syncthreads();

    const int st0   = j0 ? s_end[j0 - 1] : 0;
    const int e7    = s_end[j0 + FPB - 1];
    const int total = s_end[SEQ - 1];

    // --- 3. mask zeros for this chunk's covered rows (<= 8*15 = 120 < 128) ---
    if (tid < e7 - st0) out_mask[(b << 12) + st0 + tid] = 0.0f;

    // --- 4. pure store streaming: no loads in the loop ---
    if (tid < CH4) {
        v4f* const ob_base = out + ((size_t)(b << 12)) * CH4 + tid;
        #pragma unroll
        for (int fr = 0; fr < FPB; ++fr) {
            const int jj = j0 + fr;
            const int e  = s_end[jj];
            const int st = jj ? s_end[jj - 1] : 0;
            v4f v = vx[fr];
            v4f* ob = ob_base + (size_t)st * CH4;
            for (int t = st; t < e; ++t) {    // independent contiguous stores
                *ob = v;
                ob += CH4;
            }
        }
    }

    // --- 5. tail zero rows [total, MAXL), strided across the 64 chunks ---
    const v4f zero = (v4f){0.f, 0.f, 0.f, 0.f};
    for (int t = total + chunk; t < MAXL; t += CPB) {
        if (tid < CH4)
            out[((size_t)(b << 12) + t) * CH4 + tid] = zero;
        else if (tid == CH4)
            out_mask[(b << 12) + t] = 1.0f;
    }
}

extern "C" void kernel_launch(void* const* d_in, const int* in_sizes, int n_in,
                              void* d_out, int out_size, void* d_ws, size_t ws_size,
                              hipStream_t stream) {
    const v4f* x = (const v4f*)d_in[0];
    const v4i* dur4 = (const v4i*)d_in[1];
    const int* max_len_p = (const int*)d_in[2];
    float* out = (float*)d_out;
    float* out_mask = out + (size_t)BATCH * MAXL * CH4 * 4;

    lr_fused<<<BATCH * CPB, THREADS, 0, stream>>>(
        x, dur4, max_len_p, (v4f*)out, out_mask);
}